// Round 2
// baseline (394.034 us; speedup 1.0000x reference)
//
#include <hip/hip_runtime.h>
#include <hip/hip_bf16.h>
#include <cstdint>

typedef unsigned short ushort_t;
typedef __attribute__((ext_vector_type(8))) short short8;
typedef __attribute__((ext_vector_type(4))) float floatx4;

#define H_   16
#define DKV_ 64
#define DM_  1024
#define B_   2
#define NQ_  2048
#define NK_  2048

// fp32 -> bf16 round-to-nearest-even (inputs are well-behaved, NaN path skipped)
__device__ __forceinline__ unsigned short f2bf(float f) {
  union { float f; unsigned int u; } v; v.f = f;
  unsigned int u = v.u;
  return (unsigned short)((u + 0x7fffu + ((u >> 16) & 1u)) >> 16);
}

__device__ __forceinline__ float fexp2(float x) {
  float r; asm("v_exp_f32 %0, %1" : "=v"(r) : "v"(x)); return r;
}
__device__ __forceinline__ float frcp(float x) {
  float r; asm("v_rcp_f32 %0, %1" : "=v"(r) : "v"(x)); return r;
}

__device__ __forceinline__ floatx4 mfma16(short8 a, short8 b, floatx4 c) {
  return __builtin_amdgcn_mfma_f32_16x16x32_bf16(a, b, c, 0, 0, 0);
}

// ---------------- Projection GEMM:  C[4096,1024] = X @ W + bias -> bf16 -----
// mode 0: Q, scaled by log2(e)/8, layout [b,h,n,d]
// mode 1: K, layout [b,h,n,d]
// mode 2: V, layout [b,h,d,n]  (transposed for PV B-fragments)
constexpr int BM = 128, BN = 128, BK = 32, LDT = 40; // LDT: padded LDS row (bf16)

__global__ __launch_bounds__(256, 2) void proj_kernel(
    const float* __restrict__ Xq, const float* __restrict__ Xk, const float* __restrict__ Xv,
    const float* __restrict__ Wq, const float* __restrict__ Wk, const float* __restrict__ Wv,
    const float* __restrict__ bq, const float* __restrict__ bk, const float* __restrict__ bv,
    ushort_t* __restrict__ Qb, ushort_t* __restrict__ Kb, ushort_t* __restrict__ Vt)
{
  const int mode = blockIdx.z;
  const float* X    = (mode == 0) ? Xq : (mode == 1) ? Xk : Xv;
  const float* W    = (mode == 0) ? Wq : (mode == 1) ? Wk : Wv;
  const float* bias = (mode == 0) ? bq : (mode == 1) ? bk : bv;
  ushort_t* dst     = (mode == 0) ? Qb : (mode == 1) ? Kb : Vt;

  __shared__ ushort_t Asm[BM * LDT];
  __shared__ ushort_t Bsm[BN * LDT];

  const int tid = threadIdx.x;
  const int lane = tid & 63;
  const int wid = tid >> 6;
  const int m0 = blockIdx.y * BM;
  const int n0 = blockIdx.x * BN;
  const int c = lane & 15, g = lane >> 4;
  const int wm = wid & 1, wn = wid >> 1;
  const int mb = wm * 64, nb = wn * 64;

  floatx4 acc[4][4];
  #pragma unroll
  for (int i = 0; i < 4; i++)
    #pragma unroll
    for (int j = 0; j < 4; j++) acc[i][j] = floatx4{0.f, 0.f, 0.f, 0.f};

  const int ar = tid >> 1, ah = tid & 1;      // A staging: row, k-half
  const int bn = tid & 127, bh2 = tid >> 7;   // B staging: col n, k-half

  for (int k0 = 0; k0 < DM_; k0 += BK) {
    // global loads first (overlap with previous iteration's MFMAs)
    const floatx4* ap = (const floatx4*)(X + (m0 + ar) * DM_ + k0 + ah * 16);
    floatx4 av0 = ap[0], av1 = ap[1], av2 = ap[2], av3 = ap[3];
    const float* wp = W + (k0 + bh2 * 16) * 1024 + n0 + bn;
    float wv[16];
    #pragma unroll
    for (int j = 0; j < 16; j++) wv[j] = wp[j * 1024];

    short8 pa0, pa1, pb0, pb1;
    #pragma unroll
    for (int j = 0; j < 4; j++) {
      pa0[j]     = (short)f2bf(av0[j]);
      pa0[4 + j] = (short)f2bf(av1[j]);
      pa1[j]     = (short)f2bf(av2[j]);
      pa1[4 + j] = (short)f2bf(av3[j]);
    }
    #pragma unroll
    for (int j = 0; j < 8; j++) {
      pb0[j] = (short)f2bf(wv[j]);
      pb1[j] = (short)f2bf(wv[8 + j]);
    }

    __syncthreads();   // previous iter's fragment reads complete
    *(short8*)&Asm[ar * LDT + ah * 16]     = pa0;
    *(short8*)&Asm[ar * LDT + ah * 16 + 8] = pa1;
    *(short8*)&Bsm[bn * LDT + bh2 * 16]     = pb0;
    *(short8*)&Bsm[bn * LDT + bh2 * 16 + 8] = pb1;
    __syncthreads();

    short8 af[4], bfr[4];
    #pragma unroll
    for (int i = 0; i < 4; i++) af[i]  = *(const short8*)&Asm[(mb + i * 16 + c) * LDT + g * 8];
    #pragma unroll
    for (int j = 0; j < 4; j++) bfr[j] = *(const short8*)&Bsm[(nb + j * 16 + c) * LDT + g * 8];
    #pragma unroll
    for (int i = 0; i < 4; i++)
      #pragma unroll
      for (int j = 0; j < 4; j++) acc[i][j] = mfma16(af[i], bfr[j], acc[i][j]);
  }

  // epilogue: C/D layout col=lane&15, row=(lane>>4)*4+reg  [verified mapping]
  #pragma unroll
  for (int j = 0; j < 4; j++) {
    const int col = n0 + nb + j * 16 + c;
    const float bv_ = bias[col];
    const int h = col >> 6, d = col & 63;
    #pragma unroll
    for (int i = 0; i < 4; i++) {
      #pragma unroll
      for (int r = 0; r < 4; r++) {
        const int row = m0 + mb + i * 16 + g * 4 + r;
        const int b = row >> 11, n = row & 2047;
        float v = acc[i][j][r] + bv_;
        if (mode == 0) {
          v *= 0.18033688011112042f;  // log2(e)/8 folded into Q
          dst[((b * H_ + h) * NQ_ + n) * DKV_ + d] = f2bf(v);
        } else if (mode == 1) {
          dst[((b * H_ + h) * NQ_ + n) * DKV_ + d] = f2bf(v);
        } else {
          dst[((b * H_ + h) * DKV_ + d) * NK_ + n] = f2bf(v);
        }
      }
    }
  }
}

// ---------------- Flash attention with post-softmax group_prob gating -------
// block = (b, h, 128 q rows); 4 waves x 32 q-rows; KT=64 keys/iter.
// O_num = sum_k exp2(s-m)*gp*v ; l = sum_k exp2(s-m) ; out = O_num/l
__global__ __launch_bounds__(256, 2) void attn_kernel(
    const ushort_t* __restrict__ Qb, const ushort_t* __restrict__ Kb,
    const ushort_t* __restrict__ Vt, const float* __restrict__ gp,
    float* __restrict__ out)
{
  __shared__ ushort_t Pl[4 * 32 * 72];   // per-wave P tile, row stride 72 (16B-aligned)

  const int tid = threadIdx.x;
  const int lane = tid & 63;
  const int wid = tid >> 6;
  const int c = lane & 15, g = lane >> 4;
  const int b = blockIdx.z, h = blockIdx.y;
  const int bh = b * H_ + h;
  const int qw = blockIdx.x * 128 + wid * 32;

  const ushort_t* Qp = Qb + (size_t)bh * NQ_ * DKV_;
  const ushort_t* Kp = Kb + (size_t)bh * NK_ * DKV_;
  const ushort_t* Vp = Vt + (size_t)bh * DKV_ * NK_;
  const float* gpp = gp + (size_t)b * NQ_ * NK_;
  ushort_t* Pw = &Pl[wid * 32 * 72];

  // Q fragments resident for whole kernel (already scaled by log2e/8)
  short8 qf[2][2];
  #pragma unroll
  for (int i = 0; i < 2; i++)
    #pragma unroll
    for (int kc = 0; kc < 2; kc++)
      qf[i][kc] = *(const short8*)&Qp[(qw + i * 16 + c) * DKV_ + kc * 32 + g * 8];

  floatx4 o[2][4];
  float m2[2][4], l[2][4];
  #pragma unroll
  for (int i = 0; i < 2; i++) {
    #pragma unroll
    for (int jd = 0; jd < 4; jd++) o[i][jd] = floatx4{0.f, 0.f, 0.f, 0.f};
    #pragma unroll
    for (int r = 0; r < 4; r++) { m2[i][r] = -1e30f; l[i][r] = 0.f; }
  }

  for (int k0 = 0; k0 < NK_; k0 += 64) {
    // gp prefetch (consumed after softmax; S MFMAs hide the latency)
    float gpv[2][4][4];
    #pragma unroll
    for (int i = 0; i < 2; i++)
      #pragma unroll
      for (int r = 0; r < 4; r++) {
        const float* gq = gpp + (qw + i * 16 + g * 4 + r) * NK_ + k0 + c;
        #pragma unroll
        for (int jk = 0; jk < 4; jk++) gpv[i][jk][r] = gq[jk * 16];
      }

    // S = Q K^T (already in log2 domain thanks to folded scale)
    floatx4 s[2][4];
    #pragma unroll
    for (int i = 0; i < 2; i++)
      #pragma unroll
      for (int jk = 0; jk < 4; jk++) s[i][jk] = floatx4{0.f, 0.f, 0.f, 0.f};
    #pragma unroll
    for (int jk = 0; jk < 4; jk++) {
      const ushort_t* kp = &Kp[(k0 + jk * 16 + c) * DKV_ + g * 8];
      short8 kf0 = *(const short8*)kp;
      short8 kf1 = *(const short8*)(kp + 32);
      #pragma unroll
      for (int i = 0; i < 2; i++) {
        s[i][jk] = mfma16(qf[i][0], kf0, s[i][jk]);
        s[i][jk] = mfma16(qf[i][1], kf1, s[i][jk]);
      }
    }

    // online softmax: rowmax -> alpha -> p -> rowsum
    float alpha[2][4];
    #pragma unroll
    for (int i = 0; i < 2; i++)
      #pragma unroll
      for (int r = 0; r < 4; r++) {
        float mx = fmaxf(fmaxf(s[i][0][r], s[i][1][r]), fmaxf(s[i][2][r], s[i][3][r]));
        mx = fmaxf(mx, __shfl_xor(mx, 1));
        mx = fmaxf(mx, __shfl_xor(mx, 2));
        mx = fmaxf(mx, __shfl_xor(mx, 4));
        mx = fmaxf(mx, __shfl_xor(mx, 8));
        const float mn = fmaxf(m2[i][r], mx);
        alpha[i][r] = fexp2(m2[i][r] - mn);
        m2[i][r] = mn;
      }
    #pragma unroll
    for (int i = 0; i < 2; i++)
      #pragma unroll
      for (int r = 0; r < 4; r++) {
        float rs = 0.f;
        #pragma unroll
        for (int jk = 0; jk < 4; jk++) {
          const float p = fexp2(s[i][jk][r] - m2[i][r]);
          s[i][jk][r] = p;
          rs += p;
        }
        rs += __shfl_xor(rs, 1);
        rs += __shfl_xor(rs, 2);
        rs += __shfl_xor(rs, 4);
        rs += __shfl_xor(rs, 8);
        l[i][r] = l[i][r] * alpha[i][r] + rs;
      }
    #pragma unroll
    for (int i = 0; i < 2; i++)
      #pragma unroll
      for (int jd = 0; jd < 4; jd++)
        #pragma unroll
        for (int r = 0; r < 4; r++) o[i][jd][r] *= alpha[i][r];

    // gate with gp, write P to LDS (C-layout -> A-layout transpose)
    #pragma unroll
    for (int i = 0; i < 2; i++)
      #pragma unroll
      for (int jk = 0; jk < 4; jk++)
        #pragma unroll
        for (int r = 0; r < 4; r++)
          Pw[(i * 16 + g * 4 + r) * 72 + jk * 16 + c] = f2bf(s[i][jk][r] * gpv[i][jk][r]);

    // PV: A = P (from LDS rows), B = V^T (contiguous global short8)
    #pragma unroll
    for (int kc2 = 0; kc2 < 2; kc2++) {
      short8 af0 = *(const short8*)&Pw[(0 * 16 + c) * 72 + kc2 * 32 + g * 8];
      short8 af1 = *(const short8*)&Pw[(1 * 16 + c) * 72 + kc2 * 32 + g * 8];
      #pragma unroll
      for (int jd = 0; jd < 4; jd++) {
        short8 vf = *(const short8*)&Vp[(jd * 16 + c) * NK_ + k0 + kc2 * 32 + g * 8];
        o[0][jd] = mfma16(af0, vf, o[0][jd]);
        o[1][jd] = mfma16(af1, vf, o[1][jd]);
      }
    }
  }

  // epilogue: out[b, q, h*64+d] = fp32(O/l)  -- reference output dtype is f32
  float invl[2][4];
  #pragma unroll
  for (int i = 0; i < 2; i++)
    #pragma unroll
    for (int r = 0; r < 4; r++) invl[i][r] = frcp(l[i][r]);
  #pragma unroll
  for (int i = 0; i < 2; i++)
    #pragma unroll
    for (int jd = 0; jd < 4; jd++)
      #pragma unroll
      for (int r = 0; r < 4; r++) {
        const int row = qw + i * 16 + g * 4 + r;
        out[(size_t)(b * NQ_ + row) * 1024 + h * 64 + jd * 16 + c] =
            o[i][jd][r] * invl[i][r];
      }
}

extern "C" void kernel_launch(void* const* d_in, const int* in_sizes, int n_in,
                              void* d_out, int out_size, void* d_ws, size_t ws_size,
                              hipStream_t stream) {
  const float* queries = (const float*)d_in[0];
  const float* keys    = (const float*)d_in[1];
  const float* values  = (const float*)d_in[2];
  const float* gp      = (const float*)d_in[3];
  // d_in[4] attention_mask: intentionally unused (reference discards it)
  const float* Wq = (const float*)d_in[5];
  const float* bq = (const float*)d_in[6];
  const float* Wk = (const float*)d_in[7];
  const float* bk = (const float*)d_in[8];
  const float* Wv = (const float*)d_in[9];
  const float* bv = (const float*)d_in[10];

  ushort_t* Qb = (ushort_t*)d_ws;                       // [B,H,NQ,64] bf16, pre-scaled
  ushort_t* Kb = Qb + (size_t)B_ * H_ * NQ_ * DKV_;     // [B,H,NK,64] bf16
  ushort_t* Vt = Kb + (size_t)B_ * H_ * NK_ * DKV_;     // [B,H,64,NK] bf16 (transposed)
  float* out = (float*)d_out;

  proj_kernel<<<dim3(8, 32, 3), 256, 0, stream>>>(
      queries, keys, values, Wq, Wk, Wv, bq, bk, bv, Qb, Kb, Vt);
  attn_kernel<<<dim3(NQ_ / 128, H_, B_), 256, 0, stream>>>(Qb, Kb, Vt, gp, out);
}